// Round 5
// baseline (13591.043 us; speedup 1.0000x reference)
//
#include <hip/hip_runtime.h>
#include <hip/hip_fp16.h>

#define EPSF 1e-8f
#define SCOPE_AGT __HIP_MEMORY_SCOPE_AGENT

// T=512 B=64 IN=256 OUT=256 H=512 N=2048 C=64 R=4
// 256 blocks x 1024 threads (1/CU, cooperative co-residency), 4 blocks/batch.
// mem in registers (32 VGPR/thread). Cross-XCD exchange fence-free (relaxed
// agent atomics, coherent at L3). Barrier A exchanges ONLY h; all projections
// computed block-locally from full h (no dependent L3 assembly round-trip).
// GEMV via v_dot2_f32_f16 on fp16-packed inputs.

typedef _Float16 h2_t __attribute__((ext_vector_type(2)));

struct P5 {
  const unsigned* W2h;  // [4][416 rowpairs][512 cc] packed half2 {row 2rp, 2rp+1}
  const float* b_lstm;  // 2048
  const float* W_out;   // [512][256]
  const float* b_out;   // 256
  const float* W_key;   // [512][64]
  const float* b_key;   // 64
  const float* W_beta;  // 512
  const float* b_beta;  // 1
  const float* W_gen;   // [512][64]
  const float* b_gen;   // 64
  const float* xs;      // [512][64][256]
  float* hbuf;          // [64][512]
  float* AccP;          // [64][4][64]
  float* ZP;            // [64][4]
  float* S2P;           // [64][4]
  unsigned* ctr;        // [64][32]
  float* out;           // [512][64][256] + loss at 8388608
};

__device__ __forceinline__ float sigm(float x) { return 1.f / (1.f + __expf(-x)); }
__device__ __forceinline__ float aload(const float* p) {
  return __hip_atomic_load(p, __ATOMIC_RELAXED, SCOPE_AGT);
}
__device__ __forceinline__ void astore(float* p, float v) {
  __hip_atomic_store(p, v, __ATOMIC_RELAXED, SCOPE_AGT);
}
__device__ __forceinline__ h2_t u2h(unsigned u) {
  union { unsigned u; h2_t h; } x; x.u = u; return x.h;
}

#if defined(__has_builtin)
#if __has_builtin(__builtin_amdgcn_fdot2)
#define HAVE_FDOT2 1
#endif
#endif

__device__ __forceinline__ float dot2acc(h2_t a, h2_t b, float c) {
#ifdef HAVE_FDOT2
  return __builtin_amdgcn_fdot2(a, b, c, false);
#else
  return fmaf((float)a.x, (float)b.x, fmaf((float)a.y, (float)b.y, c));
#endif
}

__global__ void __launch_bounds__(1024, 4) dnc_b5(P5 P) {
  const int tid   = threadIdx.x;
  const int bid   = blockIdx.x;
  const int chunk = (bid >> 1) & 3;                 // XCD(bid%8) hosts one chunk value
  const int b     = ((bid >> 3) << 1) | (bid & 1);
  const int lane  = tid & 63;
  const int wv    = tid >> 6;
  const int sgrp  = lane >> 4;
  const int c4    = lane & 15;

  __shared__ _Float16 s_ih[832];   // fp16 GEMV input: rows [x(256)|h(512)|r(64)]
  __shared__ float s_h[512];       // fp32 h (projections)
  __shared__ float s_gates[512];
  __shared__ float s_c[128];
  __shared__ float s_part[4096];
  __shared__ float s_e[512];
  __shared__ float s_key[64], s_kprev[64], s_genv[64];
  __shared__ float s_wred[32];
  __shared__ float s_scal[4];      // 0:invZ_prev 1:S2_prev 2:beta 3:||key||

  unsigned* ctr = P.ctr + b * 32;

  float4 mreg[8];                  // own 512 mem slots
  float  sden[8];
#pragma unroll
  for (int i = 0; i < 8; ++i) mreg[i] = make_float4(0.f, 0.f, 0.f, 0.f);

  // init: zero h/r fp16+fp32 state, load x_0
  for (int i = 256 + tid; i < 832; i += 1024) s_ih[i] = (_Float16)0.f;
  if (tid < 512) { s_h[tid] = 0.f; s_e[tid] = 0.f; }
  if (tid < 128) {
    s_c[tid] = 0.f;
    const float2 xv = ((const float2*)P.xs)[(size_t)b * 128 + tid];
    h2_t hv; hv.x = (_Float16)xv.x; hv.y = (_Float16)xv.y;
    *(h2_t*)&s_ih[tid * 2] = hv;
  }
  if (tid < 64) s_kprev[tid] = 0.f;
  float lossacc = 0.f;
  __syncthreads();

  const int q  = tid >> 7;         // 0..7 rowpair-group
  const int cg = tid & 127;        // col-group (4 cols)
  const unsigned* wbase = P.W2h + (size_t)chunk * 212992 + (cg << 2);

  for (int t = 0; t < 512; ++t) {
    // ---- GEMV part 1: rowpairs [q*48,+48) (x+h rows), fp16 dot2
    float4 acc = make_float4(0.f, 0.f, 0.f, 0.f);
    {
      const unsigned* wp = wbase + (size_t)(q * 48) * 512;
      const _Float16* ip = s_ih + q * 96;
#pragma unroll 4
      for (int r = 0; r < 48; ++r) {
        const uint4 w = *(const uint4*)(wp + (size_t)r * 512);
        const h2_t v = *(const h2_t*)(ip + r * 2);
        acc.x = dot2acc(u2h(w.x), v, acc.x);
        acc.y = dot2acc(u2h(w.y), v, acc.y);
        acc.z = dot2acc(u2h(w.z), v, acc.z);
        acc.w = dot2acc(u2h(w.w), v, acc.w);
      }
    }

    // ---- wait barrier B_{t-1}; finalize r_{t-1} (fp16 into s_ih)
    if (t > 0) {
      if (tid == 0) {
        while (__hip_atomic_load(ctr, __ATOMIC_RELAXED, SCOPE_AGT) < 8u * (unsigned)t)
          __builtin_amdgcn_s_sleep(1);
      }
    }
    __syncthreads();                                              // #1
    float a0 = 0.f, a1 = 0.f, a2 = 0.f, a3 = 0.f;
    if (t > 0) {
      if (tid < 64) {
        const float* ap = P.AccP + b * 256 + tid;
        a0 = aload(ap); a1 = aload(ap + 64); a2 = aload(ap + 128); a3 = aload(ap + 192);
      } else if (tid == 64) {
        const float* zp = P.ZP + b * 4;
        const float* sp = P.S2P + b * 4;
        const float Z  = aload(zp) + aload(zp + 1) + aload(zp + 2) + aload(zp + 3);
        const float S2 = aload(sp) + aload(sp + 1) + aload(sp + 2) + aload(sp + 3);
        s_scal[0] = 1.f / Z;  s_scal[1] = S2;
      }
    } else if (tid == 64) {
      s_scal[0] = 0.f; s_scal[1] = 0.f;
    }
    __syncthreads();                                              // #2
    if (t > 0 && tid < 64) {
      const float iZ = s_scal[0];
      const float r = iZ * ((a0 + a1 + a2 + a3) + s_scal[1] * iZ * s_kprev[tid]);
      s_ih[768 + tid] = (_Float16)r;
    }
    __syncthreads();                                              // #3

    // ---- GEMV part 2: rowpairs [384+q*4,+4) (r rows)
    {
      const unsigned* wp = wbase + (size_t)(384 + q * 4) * 512;
      const _Float16* ip = s_ih + 768 + q * 8;
#pragma unroll
      for (int r = 0; r < 4; ++r) {
        const uint4 w = *(const uint4*)(wp + (size_t)r * 512);
        const h2_t v = *(const h2_t*)(ip + r * 2);
        acc.x = dot2acc(u2h(w.x), v, acc.x);
        acc.y = dot2acc(u2h(w.y), v, acc.y);
        acc.z = dot2acc(u2h(w.z), v, acc.z);
        acc.w = dot2acc(u2h(w.w), v, acc.w);
      }
    }
    *(float4*)&s_part[(q << 9) + (cg << 2)] = acc;
    __syncthreads();                                              // #4

    // ---- gates reduce + LSTM -> h_t (own 128 j), publish h chunk
    if (tid < 512) {
      s_gates[tid] = s_part[tid]        + s_part[512 + tid]  + s_part[1024 + tid] + s_part[1536 + tid]
                   + s_part[2048 + tid] + s_part[2560 + tid] + s_part[3072 + tid] + s_part[3584 + tid];
    }
    __syncthreads();                                              // #5
    if (tid < 128) {
      const int jl = tid, cb = chunk * 128 + jl;
      const float gi = s_gates[jl * 4 + 0] + P.b_lstm[cb];
      const float gf = s_gates[jl * 4 + 1] + P.b_lstm[512 + cb];
      const float gg = s_gates[jl * 4 + 2] + P.b_lstm[1024 + cb];
      const float go = s_gates[jl * 4 + 3] + P.b_lstm[1536 + cb];
      const float cn = sigm(gf) * s_c[jl] + sigm(gi) * tanhf(gg);
      s_c[jl] = cn;
      const float hn = sigm(go) * tanhf(cn);
      s_h[cb] = hn;
      s_ih[256 + cb] = (_Float16)hn;
      astore(P.hbuf + b * 512 + cb, hn);
    }
    __syncthreads();                                              // #6 (drains h stores)
    if (tid == 0) __hip_atomic_fetch_add(ctr, 1u, __ATOMIC_RELEASE, SCOPE_AGT);  // post A

    // ---- G1 (barrier-A shadow): apply pending rank-1 update; slot norms
    {
      const float invZp = s_scal[0];
      const float4 kp4 = ((const float4*)s_kprev)[c4];
      const int nbase = (wv * 4 + sgrp) * 8;
#pragma unroll
      for (int it = 0; it < 8; ++it) {
        float4 m4 = mreg[it];
        const float wpv = s_e[nbase + it] * invZp;   // w_{t-1}[n]  (0 at t=0)
        m4.x = fmaf(wpv, kp4.x, m4.x); m4.y = fmaf(wpv, kp4.y, m4.y);
        m4.z = fmaf(wpv, kp4.z, m4.z); m4.w = fmaf(wpv, kp4.w, m4.w);
        float ssq = m4.x * m4.x + m4.y * m4.y + m4.z * m4.z + m4.w * m4.w;
#pragma unroll
        for (int off = 1; off < 16; off <<= 1) ssq += __shfl_xor(ssq, off);
        sden[it] = fmaxf(sqrtf(ssq), EPSF);
        mreg[it] = m4;
      }
    }

    // ---- wait A; fetch peers' h; prefetch x_{t+1}
    if (tid == 0) {
      while (__hip_atomic_load(ctr, __ATOMIC_RELAXED, SCOPE_AGT) < 8u * (unsigned)t + 4u)
        __builtin_amdgcn_s_sleep(1);
    }
    __syncthreads();                                              // #7
    if (tid < 384) {
      const int pc = tid >> 7;
      const int pcc = pc + (pc >= chunk ? 1 : 0);                 // peer chunks
      const int jl = tid & 127;
      const float hv = aload(P.hbuf + b * 512 + pcc * 128 + jl);
      s_h[pcc * 128 + jl] = hv;
      s_ih[256 + pcc * 128 + jl] = (_Float16)hv;
    } else if (tid < 512 && t < 511) {
      const int rp = tid - 384;                                   // x rowpair
      const float2 xv = ((const float2*)P.xs)[((size_t)(t + 1) * 64 + b) * 128 + rp];
      h2_t hv; hv.x = (_Float16)xv.x; hv.y = (_Float16)xv.y;
      *(h2_t*)&s_ih[rp * 2] = hv;
    }
    __syncthreads();                                              // #8

    // ---- full-local projections from complete h
    {
      {  // key|gen partials: 8 rowgroups x 128 cols (64 rows each)
        const int rg = tid >> 7, cl = tid & 127;
        const float* W = (cl < 64) ? (P.W_key + cl) : (P.W_gen + (cl - 64));
        const float* hh = s_h + rg * 64;
        float a2 = 0.f;
#pragma unroll 8
        for (int r2 = 0; r2 < 64; ++r2) a2 = fmaf(hh[r2], W[(size_t)(rg * 64 + r2) * 64], a2);
        s_part[rg * 128 + cl] = a2;
      }
      {  // y own-slice partials: 16 rowgroups x 64 cols (32 rows each)
        const int rg = tid >> 6, col = tid & 63;
        const float* wp2 = P.W_out + (size_t)(rg * 32) * 256 + chunk * 64 + col;
        const float* hh = s_h + rg * 32;
        float a2 = 0.f;
#pragma unroll 8
        for (int r2 = 0; r2 < 32; ++r2) a2 = fmaf(hh[r2], wp2[(size_t)r2 * 256], a2);
        s_part[1024 + (rg << 6) + col] = a2;
      }
      {  // beta partials
        float pb = (tid < 512) ? s_h[tid] * P.W_beta[tid] : 0.f;
#pragma unroll
        for (int off = 32; off; off >>= 1) pb += __shfl_down(pb, off);
        if (tid < 512 && lane == 0) s_wred[wv] = pb;
      }
    }
    __syncthreads();                                              // #9
    if (tid < 64) {
      float v = 0.f;
#pragma unroll
      for (int k = 0; k < 8; ++k) v += s_part[k * 128 + tid];
      s_key[tid] = v + P.b_key[tid];
    } else if (tid < 128) {
      const int c = tid - 64;
      float v = 0.f;
#pragma unroll
      for (int k = 0; k < 8; ++k) v += s_part[k * 128 + 64 + c];
      s_genv[c] = v + P.b_gen[c];
    } else if (tid < 192) {
      const int col = tid - 128, oc = chunk * 64 + col;
      float v = 0.f;
#pragma unroll
      for (int k = 0; k < 16; ++k) v += s_part[1024 + k * 64 + col];
      P.out[((size_t)t * 64 + b) * 256 + oc] = v + P.b_out[oc];
    } else if (tid == 192) {
      float s = P.b_beta[0];
#pragma unroll
      for (int k = 0; k < 8; ++k) s += s_wred[k];
      s_scal[2] = (s > 20.f) ? s : log1pf(__expf(s));             // softplus
    }
    __syncthreads();                                              // #10
    if (wv == 0) {
      const float kv = s_key[lane];
      float sq = kv * kv;
#pragma unroll
      for (int off = 32; off; off >>= 1) sq += __shfl_down(sq, off);
      if (lane == 0) s_scal[3] = fmaxf(sqrtf(sq), EPSF);
    } else if (wv == 1 && chunk == 0) {
      const float d = s_key[lane] - s_genv[lane];
      float ds = d * d;
#pragma unroll
      for (int off = 32; off; off >>= 1) ds += __shfl_down(ds, off);
      if (lane == 0) lossacc += ds;                               // tid 64
    }
    __syncthreads();                                              // #11

    // ---- G2: sim/exp/acc on updated register mem
    {
      const float beta = s_scal[2], kn = s_scal[3];
      const float4 kk = ((const float4*)s_key)[c4];
      float Zp = 0.f, S2p = 0.f;
      float4 acc4 = make_float4(0.f, 0.f, 0.f, 0.f);
      const int nbase = (wv * 4 + sgrp) * 8;
#pragma unroll
      for (int it = 0; it < 8; ++it) {
        const float4 m4 = mreg[it];
        float num = m4.x * kk.x + m4.y * kk.y + m4.z * kk.z + m4.w * kk.w;
#pragma unroll
        for (int off = 1; off < 16; off <<= 1) num += __shfl_xor(num, off);
        const float e = __expf(beta * (num / (sden[it] * kn)));
        if (c4 == 0) { s_e[nbase + it] = e; Zp += e; S2p += e * e; }
        acc4.x = fmaf(e, m4.x, acc4.x); acc4.y = fmaf(e, m4.y, acc4.y);
        acc4.z = fmaf(e, m4.z, acc4.z); acc4.w = fmaf(e, m4.w, acc4.w);
      }
#pragma unroll
      for (int off = 32; off; off >>= 1) { Zp += __shfl_down(Zp, off); S2p += __shfl_down(S2p, off); }
      if (lane == 0) { s_wred[wv] = Zp; s_wred[16 + wv] = S2p; }
#pragma unroll
      for (int off = 16; off < 64; off <<= 1) {
        acc4.x += __shfl_down(acc4.x, off); acc4.y += __shfl_down(acc4.y, off);
        acc4.z += __shfl_down(acc4.z, off); acc4.w += __shfl_down(acc4.w, off);
      }
      if (lane < 16) ((float4*)s_part)[wv * 16 + lane] = acc4;
    }
    __syncthreads();                                              // #12
    if (tid < 64) {
      float a = 0.f;
#pragma unroll
      for (int w = 0; w < 16; ++w) a += s_part[w * 64 + tid];
      astore(P.AccP + (b * 4 + chunk) * 64 + tid, a);
      s_kprev[tid] = s_key[tid];
    } else if (tid == 64) {
      float Z = 0.f, S2 = 0.f;
#pragma unroll
      for (int k = 0; k < 16; ++k) { Z += s_wred[k]; S2 += s_wred[16 + k]; }
      astore(P.ZP + b * 4 + chunk, Z);
      astore(P.S2P + b * 4 + chunk, S2);
    }
    __syncthreads();                                              // #13 (drains stores)
    if (tid == 0) __hip_atomic_fetch_add(ctr, 1u, __ATOMIC_RELEASE, SCOPE_AGT);  // post B
  }

  if (chunk == 0 && tid == 64) atomicAdd(P.out + 8388608, lossacc * (1.f / 4096.f));
}

// W2h[chunk][rp][cc] = half2{W[2rp][col], W[2rp+1][col]}, col = g*512 + chunk*128 + jl,
// cc = jl*4+g. rows [0,256)=W_ih(x), [256,768)=W_hh, [768,832)=W_ih read-rows folded (R=4).
__global__ void build_w2h(const float* __restrict__ W_ih, const float* __restrict__ W_hh,
                          unsigned* __restrict__ W2h) {
  const int id = blockIdx.x * 256 + threadIdx.x;   // over 4*416*512
  if (id >= 851968) return;
  const int chunk = id / 212992;
  const int rem   = id % 212992;
  const int rp    = rem >> 9;
  const int cc    = rem & 511;
  const int jl = cc >> 2, g = cc & 3;
  const int col = g * 512 + chunk * 128 + jl;
  float v[2];
#pragma unroll
  for (int k = 0; k < 2; ++k) {
    const int row = rp * 2 + k;
    if (row < 256)      v[k] = W_ih[(size_t)row * 2048 + col];
    else if (row < 768) v[k] = W_hh[(size_t)(row - 256) * 2048 + col];
    else {
      const float* p0 = W_ih + (size_t)(256 + (row - 768) * 4) * 2048 + col;
      v[k] = p0[0] + p0[2048] + p0[4096] + p0[6144];
    }
  }
  const __half2 h2v = __floats2half2_rn(v[0], v[1]);
  W2h[id] = *(const unsigned*)&h2v;
}

extern "C" void kernel_launch(void* const* d_in, const int* in_sizes, int n_in,
                              void* d_out, int out_size, void* d_ws, size_t ws_size,
                              hipStream_t stream) {
  const float* xs     = (const float*)d_in[0];
  const float* W_ih   = (const float*)d_in[1];
  const float* W_hh   = (const float*)d_in[2];
  const float* b_lstm = (const float*)d_in[3];
  const float* W_out  = (const float*)d_in[4];
  const float* b_out  = (const float*)d_in[5];
  const float* W_key  = (const float*)d_in[6];
  const float* b_key  = (const float*)d_in[7];
  const float* W_beta = (const float*)d_in[8];
  const float* b_beta = (const float*)d_in[9];
  const float* W_gen  = (const float*)d_in[10];
  const float* b_gen  = (const float*)d_in[11];
  float* out = (float*)d_out;

  float* ws = (float*)d_ws;
  unsigned* W2h = (unsigned*)ws;          //   851,968 u32
  float* hbuf  = ws     + 851968;         //    32,768
  float* AccP  = hbuf   + 32768;          //    16,384
  float* ZP    = AccP   + 16384;          //       256
  float* S2P   = ZP     + 256;            //       256
  unsigned* ctr = (unsigned*)(S2P + 256); //     2,048 u32

  hipMemsetAsync(ctr, 0, 2048 * sizeof(unsigned), stream);
  hipMemsetAsync(out + 8388608, 0, sizeof(float), stream);

  build_w2h<<<dim3(3328), dim3(256), 0, stream>>>(W_ih, W_hh, W2h);

  P5 prm;
  prm.W2h = W2h;      prm.b_lstm = b_lstm;
  prm.W_out = W_out;  prm.b_out = b_out;
  prm.W_key = W_key;  prm.b_key = b_key;
  prm.W_beta = W_beta; prm.b_beta = b_beta;
  prm.W_gen = W_gen;  prm.b_gen = b_gen;
  prm.xs = xs;
  prm.hbuf = hbuf; prm.AccP = AccP; prm.ZP = ZP; prm.S2P = S2P;
  prm.ctr = ctr;  prm.out = out;

  void* kargs[] = { &prm };
  hipLaunchCooperativeKernel(reinterpret_cast<void*>(&dnc_b5),
                             dim3(256), dim3(1024), kargs, 0, stream);
}